// Round 8
// baseline (136.493 us; speedup 1.0000x reference)
//
#include <hip/hip_runtime.h>
#include <hip/hip_bf16.h>
#include <cstddef>

#define NHEADS 9
#define D 32
#define SQ 4096
#define ZSPLIT 8
#define MBLK (SQ / ZSPLIT)     // 512 m per block
#define CHUNKS (MBLK / 64)     // 8 chunks of 64 m
#define PERIODS (CHUNKS / 2)   // 4 double-chunk barrier periods

typedef __attribute__((ext_vector_type(8))) short bf16x8;
typedef __attribute__((ext_vector_type(4))) float f32x4;

__device__ __forceinline__ unsigned int f2bf(float f) {
    unsigned int u = __float_as_uint(f);
    u += 0x7fffu + ((u >> 16) & 1u);
    return u >> 16;
}

// pack two f32 into bf16x2 by TRUNCATION: one v_perm_b32.
__device__ __forceinline__ unsigned int trunc_pk(float lo, float hi) {
    return __builtin_amdgcn_perm(__float_as_uint(hi), __float_as_uint(lo),
                                 0x07060302u);
}

// Pack 8 scores (two QK C-tiles) then relu on bf16 BIT PATTERNS:
// negative bf16 == negative i16, so relu == v_pk_max_i16(p, 0).
__device__ __forceinline__ bf16x8 relu_pack8(f32x4 s1, f32x4 s2) {
    union { unsigned int u[4]; bf16x8 v; } P;
    P.u[0] = trunc_pk(s1[0], s1[1]);
    P.u[1] = trunc_pk(s1[2], s1[3]);
    P.u[2] = trunc_pk(s2[0], s2[1]);
    P.u[3] = trunc_pk(s2[2], s2[3]);
    const bf16x8 z = {0, 0, 0, 0, 0, 0, 0, 0};
    return __builtin_elementwise_max(P.v, z);   // v_pk_max_i16 x4
}

// async global->LDS DMA, 16B per lane; LDS dest = wave-uniform base + lane*16.
__device__ __forceinline__ void gload_lds16(const unsigned short* g,
                                            unsigned short* l) {
    __builtin_amdgcn_global_load_lds(
        (const __attribute__((address_space(1))) unsigned int*)g,
        (__attribute__((address_space(3))) unsigned int*)l, 16, 0, 0);
}

// ---------------------------------------------------------------------------
// Prep v8: ONE THREAD PER (bh, n) computing all 32 d.
// Round-7 post-mortem: the old 4-threads-per-n layout loaded the same 6 pixel
// + 16 feat floats 4x each, and per-lane hd made every weight access a VECTOR
// load. Now: vector-load traffic /4, and h is BLOCK-UNIFORM so all Wq/Wk/Wv/
// Wt/biases compile to s_load (scalar cache, one fetch per wave).
// Output layouts unchanged:
//   Q: [bh][n][d] contiguous 64B/n.
//   K: chunk-slot-permuted [bh][chunk=n>>6][slot(n&63)][d].
//   V: fragment-ordered per 32-m chunk 2KB block
//      (bh*128 + m>>5)*1024 + (d>>4)*512 + ((m>>3)&3)*128 + (d&15)*8 + (m&7)
// V transpose via LDS (conflict-free column writes, row-contig reads).
// ---------------------------------------------------------------------------
__global__ __launch_bounds__(128) void prep_kernel(
    const float* __restrict__ x2, const float* __restrict__ x1,
    const float* __restrict__ feat1,
    const float* __restrict__ Wq, const float* __restrict__ bq,
    const float* __restrict__ Wk, const float* __restrict__ bk,
    const float* __restrict__ Wv, const float* __restrict__ bv,
    const float* __restrict__ Wt, const float* __restrict__ bt,
    unsigned short* __restrict__ Qb, unsigned short* __restrict__ Kb,
    unsigned short* __restrict__ Vt, float* __restrict__ tbuf)
{
    __shared__ unsigned short Vls[32 * 136];   // [d][n_local 128], stride 136

    const int tid = threadIdx.x;       // n-local 0..127
    const int blk = blockIdx.x;        // 0..575
    const int bh  = blk >> 5;          // 0..17  (block-uniform)
    const int nr  = blk & 31;          // 128-n range within bh
    const int n   = nr * 128 + tid;
    const int h   = bh % NHEADS;       // scalar -> weight reads are s_load
    const int b   = bh / NHEADS;

    float xs0 = x2[((size_t)b * 3 + 0) * SQ + n];
    float xs1 = x2[((size_t)b * 3 + 1) * SQ + n];
    float xs2 = x2[((size_t)b * 3 + 2) * SQ + n];
    float ys0 = x1[((size_t)b * 3 + 0) * SQ + n];
    float ys1 = x1[((size_t)b * 3 + 1) * SQ + n];
    float ys2 = x1[((size_t)b * 3 + 2) * SQ + n];

    // bilinear upsample coords: src = i*0.5 - 0.25 (half-pixel)
    int yy = n >> 6, xx = n & 63;
    int jy = yy >> 1, jx = xx >> 1;
    int j0, j1, i0, i1; float wy0, wy1, wx0, wx1;
    if (yy & 1) { j0 = jy; j1 = (jy < 31) ? jy + 1 : 31; wy0 = 0.75f; wy1 = 0.25f; }
    else        { j0 = (jy > 0) ? jy - 1 : 0; j1 = jy;   wy0 = 0.25f; wy1 = 0.75f; }
    if (xx & 1) { i0 = jx; i1 = (jx < 31) ? jx + 1 : 31; wx0 = 0.75f; wx1 = 0.25f; }
    else        { i0 = (jx > 0) ? jx - 1 : 0; i1 = jx;   wx0 = 0.25f; wx1 = 0.75f; }

    float fu[4];
#pragma unroll
    for (int c = 0; c < 4; ++c) {
        const float* f = feat1 + ((size_t)b * 4 + c) * 1024;
        fu[c] = wy0 * (wx0 * f[j0 * 32 + i0] + wx1 * f[j0 * 32 + i1]) +
                wy1 * (wx0 * f[j1 * 32 + i0] + wx1 * f[j1 * 32 + i1]);
    }

    unsigned int qp[16], kp[16];
    float tpart = 0.0f;
#pragma unroll
    for (int d = 0; d < 32; ++d) {
        int hd = h * D + d;            // scalar
        float q = bq[hd] + Wq[hd * 3] * xs0 + Wq[hd * 3 + 1] * xs1 + Wq[hd * 3 + 2] * xs2;
        float k = bk[hd] + Wk[hd * 3] * ys0 + Wk[hd * 3 + 1] * ys1 + Wk[hd * 3 + 2] * ys2;
        float v = bv[hd] + Wv[hd * 4] * fu[0] + Wv[hd * 4 + 1] * fu[1] +
                  Wv[hd * 4 + 2] * fu[2] + Wv[hd * 4 + 3] * fu[3];
        tpart += q * Wt[d];
        unsigned int qb_ = f2bf(q), kb_ = f2bf(k);
        if (d & 1) { qp[d >> 1] |= qb_ << 16; kp[d >> 1] |= kb_ << 16; }
        else       { qp[d >> 1]  = qb_;       kp[d >> 1]  = kb_; }
        Vls[d * 136 + tid] = (unsigned short)f2bf(v);   // conflict-free column
    }
    tbuf[(size_t)bh * SQ + n] = tpart + bt[0];

    {   // Q: contiguous 64B per n
        size_t qa = ((size_t)bh * SQ + n) * D;
#pragma unroll
        for (int r4 = 0; r4 < 4; ++r4)
            *(uint4*)(Qb + qa + r4 * 8) =
                make_uint4(qp[r4 * 4], qp[r4 * 4 + 1], qp[r4 * 4 + 2], qp[r4 * 4 + 3]);
    }
    {   // K: permuted-slot row (bijective within each 64-row chunk)
        int nl_  = n & 63;
        int slot = (nl_ & 32) + 4 * ((nl_ >> 3) & 3) + (nl_ & 3) + ((nl_ & 4) << 2);
        size_t ka = ((size_t)bh * SQ + (n & ~63) + slot) * D;
#pragma unroll
        for (int r4 = 0; r4 < 4; ++r4)
            *(uint4*)(Kb + ka + r4 * 8) =
                make_uint4(kp[r4 * 4], kp[r4 * 4 + 1], kp[r4 * 4 + 2], kp[r4 * 4 + 3]);
    }

    __syncthreads();
    // V write-out in fragment order: 512 uint4 stores, 4 per thread.
#pragma unroll
    for (int rep = 0; rep < 4; ++rep) {
        int li  = rep * 128 + tid;     // 0..511
        int r   = li >> 4;             // d 0..31
        int oct = li & 15;             // n-octet 0..15 within the 128-n range
        const unsigned short* src = &Vls[r * 136 + oct * 8];
        uint4 w = make_uint4(*(const unsigned int*)src,
                             *(const unsigned int*)(src + 2),
                             *(const unsigned int*)(src + 4),
                             *(const unsigned int*)(src + 6));
        size_t dst = ((size_t)bh * 128 + nr * 4 + (oct >> 2)) * 1024
                   + (r >> 4) * 512 + (oct & 3) * 128 + (r & 15) * 8;
        *(uint4*)(Vt + dst) = w;
    }
}

// ---------------------------------------------------------------------------
// Attention v8: 8-wave blocks, global_load_lds staging, counted vmcnt —
// now with TWO chunks (128 m) per barrier period: 3 slots x 16KB (48KB LDS),
// 4 barriers per block instead of 8, prefetch issued 2 periods before its
// vmcnt wait (~2x round-7 cover), and 64 consecutive MFMA per wave between
// syncs (less phase-convoy). Per-wave VGPR state unchanged (~64, round-5
// invariant). Waves 0-3 stage K quarters, 4-7 V quarters; each wave issues
// 2 DMA ops per period. vmcnt never drains to 0 in the loop.
// Epilogue: plain stores of per-(bh,zz) partials (no atomics — round 2).
// ---------------------------------------------------------------------------
#define STEP_COMPUTE(K1, K2, VL, VH)                                           \
    {                                                                          \
        f32x4 sA1 = __builtin_amdgcn_mfma_f32_16x16x32_bf16(K1, qfA, ciA, 0, 0, 0);\
        f32x4 sA2 = __builtin_amdgcn_mfma_f32_16x16x32_bf16(K2, qfA, ciA, 0, 0, 0);\
        f32x4 sB1 = __builtin_amdgcn_mfma_f32_16x16x32_bf16(K1, qfB, ciB, 0, 0, 0);\
        f32x4 sB2 = __builtin_amdgcn_mfma_f32_16x16x32_bf16(K2, qfB, ciB, 0, 0, 0);\
        f32x4 sC1 = __builtin_amdgcn_mfma_f32_16x16x32_bf16(K1, qfC, ciC, 0, 0, 0);\
        f32x4 sC2 = __builtin_amdgcn_mfma_f32_16x16x32_bf16(K2, qfC, ciC, 0, 0, 0);\
        f32x4 sD1 = __builtin_amdgcn_mfma_f32_16x16x32_bf16(K1, qfD, ciD, 0, 0, 0);\
        f32x4 sD2 = __builtin_amdgcn_mfma_f32_16x16x32_bf16(K2, qfD, ciD, 0, 0, 0);\
        bf16x8 pA = relu_pack8(sA1, sA2);                                      \
        bf16x8 pB = relu_pack8(sB1, sB2);                                      \
        bf16x8 pC = relu_pack8(sC1, sC2);                                      \
        bf16x8 pD = relu_pack8(sD1, sD2);                                      \
        accAl = __builtin_amdgcn_mfma_f32_16x16x32_bf16(VL, pA, accAl, 0, 0, 0);\
        accAh = __builtin_amdgcn_mfma_f32_16x16x32_bf16(VH, pA, accAh, 0, 0, 0);\
        accBl = __builtin_amdgcn_mfma_f32_16x16x32_bf16(VL, pB, accBl, 0, 0, 0);\
        accBh = __builtin_amdgcn_mfma_f32_16x16x32_bf16(VH, pB, accBh, 0, 0, 0);\
        accCl = __builtin_amdgcn_mfma_f32_16x16x32_bf16(VL, pC, accCl, 0, 0, 0);\
        accCh = __builtin_amdgcn_mfma_f32_16x16x32_bf16(VH, pC, accCh, 0, 0, 0);\
        accDl = __builtin_amdgcn_mfma_f32_16x16x32_bf16(VL, pD, accDl, 0, 0, 0);\
        accDh = __builtin_amdgcn_mfma_f32_16x16x32_bf16(VH, pD, accDh, 0, 0, 0);\
    }

__global__ __launch_bounds__(512, 4) void attn_kernel(
    const unsigned short* __restrict__ Qb,
    const unsigned short* __restrict__ Kb,
    const unsigned short* __restrict__ Vt,
    const float* __restrict__ tbuf,
    const float* __restrict__ Wp,
    float* __restrict__ ofp)
{
    __shared__ __align__(16) unsigned short Kls[3][4096];   // 3 x 8KB
    __shared__ __align__(16) unsigned short Vls3[3][4096];  // 3 x 8KB

    // XCD-aware bijective decode: lin -> (xcd 0..7, q 0..143) ->
    // (group-local 0..17, xblk 0..7); group = xcd*18+gl -> (bh, z).
    const int lin  = blockIdx.x;
    const int xcd  = lin & 7;
    const int q8   = lin >> 3;           // 0..143
    const int xblk = q8 & 7;
    const int gl   = q8 >> 3;            // 0..17
    const int grp  = xcd * 18 + gl;      // 0..143
    const int bh   = grp >> 3;           // 0..17
    const int zz   = grp & 7;            // 0..7
    const int h    = bh % NHEADS;
    const int n0   = xblk * 512;
    const int mc0  = zz * MBLK;
    const int tid  = threadIdx.x;
    const int wave = tid >> 6;           // 0..7
    const int lane = tid & 63;
    const int l15  = lane & 15;
    const int quad = lane >> 4;

    const int nw = n0 + wave * 64;

    // Q as B-fragment: B[d=quad*8+j][n=l15], 4 tiles at n offsets 0/16/32/48
    const unsigned short* qbase = Qb + ((size_t)bh * SQ + nw + l15) * D + quad * 8;
    bf16x8 qfA = *(const bf16x8*)(qbase);
    bf16x8 qfB = *(const bf16x8*)(qbase + 16 * D);
    bf16x8 qfC = *(const bf16x8*)(qbase + 32 * D);
    bf16x8 qfD = *(const bf16x8*)(qbase + 48 * D);

    const float SQRT32 = 5.656854249492381f;
    const float* tb = tbuf + (size_t)bh * SQ + nw + l15;
    float TA = tb[0]  * SQRT32;
    float TB = tb[16] * SQRT32;
    float TC = tb[32] * SQRT32;
    float TD = tb[48] * SQRT32;
    const f32x4 ciA = {-TA, -TA, -TA, -TA};
    const f32x4 ciB = {-TB, -TB, -TB, -TB};
    const f32x4 ciC = {-TC, -TC, -TC, -TC};
    const f32x4 ciD = {-TD, -TD, -TD, -TD};

    // staging: waves 0-3 stage K quarters, waves 4-7 stage V quarters.
    const int qtr = wave & 3;
    const unsigned short* Sg =
        (wave < 4) ? (Kb + ((size_t)bh * SQ + mc0) * D + qtr * 512 + lane * 8)
                   : (Vt + ((size_t)bh * 128 + (mc0 >> 5)) * 1024 + qtr * 512 + lane * 8);
    const int sdoff = qtr * 512;

    // fragment read offsets within a chunk (halfwords)
    const int koff = l15 * 32 + quad * 8;
    const int voff = lane * 8;

// stage both chunks of period P into slot S (2 DMA ops per wave)
#define ISSUE2(P, S)                                                           \
    gload_lds16(Sg + (size_t)(P) * 4096,                                       \
                ((wave < 4) ? &Kls[S][sdoff] : &Vls3[S][sdoff]));              \
    gload_lds16(Sg + (size_t)(P) * 4096 + 2048,                                \
                ((wave < 4) ? &Kls[S][2048 + sdoff] : &Vls3[S][2048 + sdoff]));

#define CCHUNK(S, OFF)                                                         \
    {                                                                          \
        const unsigned short* Kp = &Kls[S][OFF];                               \
        const unsigned short* Vp = &Vls3[S][OFF];                              \
        bf16x8 k1 = *(const bf16x8*)(Kp + koff);                               \
        bf16x8 k2 = *(const bf16x8*)(Kp + 512 + koff);                         \
        bf16x8 vl = *(const bf16x8*)(Vp + voff);                               \
        bf16x8 vh = *(const bf16x8*)(Vp + 512 + voff);                         \
        __builtin_amdgcn_s_setprio(1);                                         \
        STEP_COMPUTE(k1, k2, vl, vh);                                          \
        __builtin_amdgcn_s_setprio(0);                                         \
        k1 = *(const bf16x8*)(Kp + 1024 + koff);                               \
        k2 = *(const bf16x8*)(Kp + 1536 + koff);                               \
        vl = *(const bf16x8*)(Vp + 1024 + voff);                               \
        vh = *(const bf16x8*)(Vp + 1536 + voff);                               \
        __builtin_amdgcn_s_setprio(1);                                         \
        STEP_COMPUTE(k1, k2, vl, vh);                                          \
        __builtin_amdgcn_s_setprio(0);                                         \
    }

    f32x4 accAl = {0.f,0.f,0.f,0.f}, accAh = {0.f,0.f,0.f,0.f};
    f32x4 accBl = {0.f,0.f,0.f,0.f}, accBh = {0.f,0.f,0.f,0.f};
    f32x4 accCl = {0.f,0.f,0.f,0.f}, accCh = {0.f,0.f,0.f,0.f};
    f32x4 accDl = {0.f,0.f,0.f,0.f}, accDh = {0.f,0.f,0.f,0.f};

    // prologue: periods 0,1 in flight (2 vm-ops each per wave)
    ISSUE2(0, 0);
    ISSUE2(1, 1);

#pragma unroll
    for (int p = 0; p < PERIODS; ++p) {
        // period p landed; period p+1 stays in flight (never vmcnt 0)
        asm volatile("s_waitcnt vmcnt(2)" ::: "memory");
        __builtin_amdgcn_s_barrier();    // publishes all waves' quarters
        {
            const int np = (p + 2 < PERIODS) ? p + 2 : PERIODS - 1;  // tail dup
            ISSUE2(np, (p + 2) % 3);     // slot last read at period p-1
        }
        CCHUNK(p % 3, 0);
        CCHUNK(p % 3, 2048);
    }
    asm volatile("s_waitcnt vmcnt(0)" ::: "memory");   // drain tail dups

    // lane holds out^T[d = quad*4+r (lo) / 16+... (hi)][n] (x sqrt(32)*3000).
    // Project 288->4 with Wp, apply deferred scale, reduce quads, and STORE
    // the per-(bh,zz) partial into this block's unique of_part region.
    const float s1 = 5.892556509887896e-05f;   // 1/(sqrt(32)*3000)
    const float* wph = Wp + h * D + quad * 4;
    float* obase = ofp + ((size_t)(bh * 8 + zz) * 4) * SQ + nw + l15;
#pragma unroll
    for (int o = 0; o < 4; ++o) {
        float cA = 0.f, cB = 0.f, cC = 0.f, cD = 0.f;
#pragma unroll
        for (int r = 0; r < 4; ++r) {
            float wlo = wph[o * 288 + r], whi = wph[o * 288 + 16 + r];
            cA += accAl[r] * wlo + accAh[r] * whi;
            cB += accBl[r] * wlo + accBh[r] * whi;
            cC += accCl[r] * wlo + accCh[r] * whi;
            cD += accDl[r] * wlo + accDh[r] * whi;
        }
        cA += __shfl_xor(cA, 16); cA += __shfl_xor(cA, 32);
        cB += __shfl_xor(cB, 16); cB += __shfl_xor(cB, 32);
        cC += __shfl_xor(cC, 16); cC += __shfl_xor(cC, 32);
        cD += __shfl_xor(cD, 16); cD += __shfl_xor(cD, 32);
        if (quad == 0) {
            float* ob = obase + (size_t)o * SQ;
            ob[0]  = cA * s1;
            ob[16] = cB * s1;
            ob[32] = cC * s1;
            ob[48] = cD * s1;
        }
    }
}

// ---------------------------------------------------------------------------
// Final: 72-way partial reduction (9 h x 8 zz) fused with 2x2-mean
// downsample + bias + residual; both tuple outputs.
// 65536 threads: 8 per output (one zz-slice each, 9-h loop), shfl reduce.
// ---------------------------------------------------------------------------
__global__ __launch_bounds__(256) void final_kernel(
    const float* __restrict__ ofp,
    const float* __restrict__ sff,
    const float* __restrict__ bp,
    float* __restrict__ dout)
{
    int t = blockIdx.x * 256 + threadIdx.x;   // 0..65535
    int out = t >> 3;                         // 0..8191 output index
    int s   = t & 7;                          // zz slice
    int i  = out & 31;
    int jj = (out >> 5) & 31;
    int bo = out >> 10;
    int o  = bo & 3;
    int b  = bo >> 2;
    int nbase = (jj * 2) * 64 + i * 2;

    float acc = 0.0f;
#pragma unroll
    for (int h = 0; h < NHEADS; ++h) {
        const float* src = ofp +
            ((size_t)(((b * NHEADS + h) * 8 + s) * 4 + o)) * SQ + nbase;
        acc += src[0] + src[1] + src[64] + src[65];
    }
    acc += __shfl_xor(acc, 1);
    acc += __shfl_xor(acc, 2);
    acc += __shfl_xor(acc, 4);
    if (s == 0) {
        float dval = 0.25f * acc + bp[o];
        dout[out]        = sff[out] + dval;
        dout[8192 + out] = dval;
    }
}

extern "C" void kernel_launch(void* const* d_in, const int* in_sizes, int n_in,
                              void* d_out, int out_size, void* d_ws, size_t ws_size,
                              hipStream_t stream)
{
    const float* second_frame = (const float*)d_in[0];
    const float* first_frame  = (const float*)d_in[1];
    const float* sff          = (const float*)d_in[2];
    const float* ffa          = (const float*)d_in[3];
    const float* Wq = (const float*)d_in[4];
    const float* bq = (const float*)d_in[5];
    const float* Wk = (const float*)d_in[6];
    const float* bk = (const float*)d_in[7];
    const float* Wv = (const float*)d_in[8];
    const float* bv = (const float*)d_in[9];
    const float* Wp = (const float*)d_in[10];
    const float* bp = (const float*)d_in[11];
    const float* Wt = (const float*)d_in[12];
    const float* bt = (const float*)d_in[13];
    float* out = (float*)d_out;

    char* ws = (char*)d_ws;
    const size_t QKV = (size_t)2 * NHEADS * SQ * D * sizeof(unsigned short);
    unsigned short* Qb = (unsigned short*)ws;
    unsigned short* Kb = (unsigned short*)(ws + QKV);
    unsigned short* Vt = (unsigned short*)(ws + 2 * QKV);
    float* tbuf = (float*)(ws + 3 * QKV);
    // of_part[18 bh][8 zz][4 o][4096 n] = 9.44 MB of partials
    float* ofp  = (float*)(ws + 3 * QKV + (size_t)2 * NHEADS * SQ * sizeof(float));

    prep_kernel<<<576, 128, 0, stream>>>(second_frame, first_frame, ffa,
                                         Wq, bq, Wk, bk, Wv, bv, Wt, bt,
                                         Qb, Kb, Vt, tbuf);
    attn_kernel<<<8 * 18 * ZSPLIT, 512, 0, stream>>>(Qb, Kb, Vt, tbuf, Wp, ofp);
    final_kernel<<<256, 256, 0, stream>>>(ofp, sff, bp, out);
}